// Round 4
// baseline (1904.310 us; speedup 1.0000x reference)
//
#include <hip/hip_runtime.h>

// Problem constants (from reference)
constexpr int B_   = 4;
constexpr int N_   = 16384;
constexpr int NOUT = 1170;   // 16384 // 14
constexpr int D_   = 128;
constexpr int O_   = 256;

typedef float f32x2 __attribute__((ext_vector_type(2)));
typedef unsigned long long u64;

// DPP-based wave max: 6 VALU ops instead of 6 ds_swizzle shuffles.
// quad_perm[1,0,3,2]=0xB1 (xor1), quad_perm[2,3,0,1]=0x4E (xor2),
// row_half_mirror=0x141, row_mirror=0x140, row_bcast15=0x142, row_bcast31=0x143.
// After all six, lane 63 holds the wave max (update_dpp keeps old where the
// bcast pattern has no source lane, so partial maxima are preserved).
template <int CTRL>
__device__ __forceinline__ float dpp_fmax(float x) {
  int yi = __builtin_amdgcn_update_dpp(__float_as_int(x), __float_as_int(x),
                                       CTRL, 0xF, 0xF, false);
  return fmaxf(x, __int_as_float(yi));
}

__device__ __forceinline__ u64 umax64(u64 a, u64 b) { return a > b ? a : b; }

// ---------------- FPS kernel ----------------
// One block per batch. 1024 threads x 16 points (consecutive ownership:
// thread t owns points [t*16, t*16+16) so lane order == global index order).
// Arrays = 64 VGPRs, pinned resident via asm "+v" (blocks invariant-load
// remat that plagued rounds 1-3: VGPR_Count 48/88/92 < needed).
// Per step: pk-f32 distance loop -> DPP wave max -> ballot/ctz/readlane for
// the wave's first-max index -> u64 key to LDS -> ONE barrier -> redundant
// 16-key tree -> uniform coord load. Exact np semantics throughout.
constexpr int TPB_FPS = 1024;
constexpr int PPT   = N_ / TPB_FPS;  // 16 points per thread
constexpr int NPAIR = PPT / 2;       // 8 f32x2 pairs
constexpr int NW    = TPB_FPS / 64;  // 16 waves

__global__ __launch_bounds__(TPB_FPS)
__attribute__((amdgpu_waves_per_eu(4, 4)))
void fps_kernel(const float* __restrict__ pcd_x,
                int* __restrict__ sel,        // [B, NOUT] (workspace)
                float* __restrict__ out_c) {  // query_c [B, NOUT, 3]
  const int b = blockIdx.x;
  const int t = threadIdx.x;
  const float* __restrict__ P = pcd_x + (size_t)b * N_ * 3;
  const int base = t * PPT;  // consecutive ownership

  f32x2 x[NPAIR], y[NPAIR], z[NPAIR], dm[NPAIR];
#pragma unroll
  for (int k = 0; k < NPAIR; ++k) {
    const int p0 = base + 2 * k;
    x[k]  = f32x2{P[p0 * 3 + 0], P[p0 * 3 + 3]};
    y[k]  = f32x2{P[p0 * 3 + 1], P[p0 * 3 + 4]};
    z[k]  = f32x2{P[p0 * 3 + 2], P[p0 * 3 + 5]};
    dm[k] = f32x2{1e10f, 1e10f};
  }
  // Pin arrays in VGPRs: asm output can't be rematerialized from memory.
#pragma unroll
  for (int k = 0; k < NPAIR; ++k) {
    asm volatile("" : "+v"(x[k]), "+v"(y[k]), "+v"(z[k]), "+v"(dm[k]));
  }

  __shared__ u64 s_key[2][NW] __attribute__((aligned(16)));

  // step 0: deterministic start at index 0
  float lx = P[0], ly = P[1], lz = P[2];
  if (t == 0) {
    sel[b * NOUT + 0] = 0;
    out_c[((size_t)b * NOUT + 0) * 3 + 0] = lx;
    out_c[((size_t)b * NOUT + 0) * 3 + 1] = ly;
    out_c[((size_t)b * NOUT + 0) * 3 + 2] = lz;
  }

  for (int step = 1; step < NOUT; ++step) {
    const int par = step & 1;
    const f32x2 lxx = {lx, lx}, lyy = {ly, ly}, lzz = {lz, lz};
    f32x2 bv2 = {-1.0f, -1.0f};
    {
#pragma clang fp contract(off)
#pragma unroll
      for (int k = 0; k < NPAIR; ++k) {
        // EXACT np order per component: ((dx*dx + dy*dy) + dz*dz), no FMA
        const f32x2 dx = x[k] - lxx;
        const f32x2 dy = y[k] - lyy;
        const f32x2 dz = z[k] - lzz;
        const f32x2 s  = (dx * dx + dy * dy) + dz * dz;
        f32x2 nd;
        nd.x = fminf(dm[k].x, s.x);
        nd.y = fminf(dm[k].y, s.y);
        dm[k] = nd;
        bv2.x = fmaxf(bv2.x, nd.x);
        bv2.y = fmaxf(bv2.y, nd.y);
      }
    }
    const float bv = fmaxf(bv2.x, bv2.y);

    // wave max via DPP (VALU-only, ~60 cyc chain)
    float wm = bv;
    wm = dpp_fmax<0xB1>(wm);
    wm = dpp_fmax<0x4E>(wm);
    wm = dpp_fmax<0x141>(wm);
    wm = dpp_fmax<0x140>(wm);
    wm = dpp_fmax<0x142>(wm);
    wm = dpp_fmax<0x143>(wm);
    const float wmax =
        __int_as_float(__builtin_amdgcn_readlane(__float_as_int(wm), 63));

    // in-thread first-max index (descending scan: last write = smallest j)
    int bi = 0;
#pragma unroll
    for (int k = NPAIR - 1; k >= 0; --k) {
      if (dm[k].y == bv) bi = base + 2 * k + 1;
      if (dm[k].x == bv) bi = base + 2 * k;
    }

    // wave's first-max lane: lane order == index order (consecutive owners)
    const unsigned long long mask = __ballot(bv == wmax);
    const int flane = __builtin_ctzll(mask);
    const int idx_w = __builtin_amdgcn_readlane(bi, flane);

    // u64 key: (valbits<<32) | ~idx ; max -> max val, tie -> min index
    const u64 key =
        ((u64)__float_as_uint(wmax) << 32) | (unsigned)(~idx_w);
    if ((t & 63) == 0) s_key[par][t >> 6] = key;
    __syncthreads();  // the only barrier per step (double-buffered s_key)

    // redundant 16-key tree (broadcast b128 reads, depth 4)
    const ulonglong2* kp =
        reinterpret_cast<const ulonglong2*>(&s_key[par][0]);
    u64 m[8];
#pragma unroll
    for (int i = 0; i < 8; ++i) {
      const ulonglong2 v = kp[i];
      m[i] = umax64(v.x, v.y);
    }
    const u64 q0 = umax64(umax64(m[0], m[1]), umax64(m[2], m[3]));
    const u64 q1 = umax64(umax64(m[4], m[5]), umax64(m[6], m[7]));
    const u64 kmax = umax64(q0, q1);

    int ri = (int)(~(unsigned)kmax);
    ri = __builtin_amdgcn_readfirstlane(ri);  // uniform -> scalar loads

    lx = P[ri * 3 + 0];
    ly = P[ri * 3 + 1];
    lz = P[ri * 3 + 2];
    if (t == 0) {
      sel[b * NOUT + step] = ri;
      out_c[((size_t)b * NOUT + step) * 3 + 0] = lx;
      out_c[((size_t)b * NOUT + step) * 3 + 1] = ly;
      out_c[((size_t)b * NOUT + step) * 3 + 2] = lz;
    }
  }
}

// ---------------- projection + gathers ----------------
// out_query_f[row, :] = tgt[b, sel[row], :] @ W + bias ; rows = B*NOUT.
// 4 rows per 256-thread block; thread t owns output column t.
constexpr int TPB_PROJ = 256;
constexpr int RPB = 4;

__global__ __launch_bounds__(TPB_PROJ)
void proj_kernel(const float* __restrict__ tgt,
                 const float* __restrict__ pcd_v,
                 const float* __restrict__ W,
                 const float* __restrict__ bias,
                 const int* __restrict__ sel,
                 float* __restrict__ out_f,    // [B*NOUT, 256]
                 float* __restrict__ out_v) {  // [B*NOUT, 9]
  const int t = threadIdx.x;
  const int row0 = blockIdx.x * RPB;

  __shared__ float sA[RPB * D_];
  __shared__ int   sIdx[RPB];

  if (t < RPB) {
    const int row = row0 + t;
    const int b = row / NOUT;
    sIdx[t] = b * N_ + sel[row];   // absolute point index in [B*N)
  }
  __syncthreads();

#pragma unroll
  for (int l = 0; l < RPB * D_ / TPB_PROJ; ++l) {  // 2 iterations
    const int e = t + l * TPB_PROJ;
    const int r = e >> 7;
    const int k = e & (D_ - 1);
    sA[e] = tgt[(size_t)sIdx[r] * D_ + k];
  }
  __syncthreads();

  float acc0 = 0.f, acc1 = 0.f, acc2 = 0.f, acc3 = 0.f;
#pragma unroll 8
  for (int k = 0; k < D_; ++k) {
    const float w = W[k * O_ + t];       // coalesced across threads
    acc0 = fmaf(sA[0 * D_ + k], w, acc0);  // LDS broadcast reads
    acc1 = fmaf(sA[1 * D_ + k], w, acc1);
    acc2 = fmaf(sA[2 * D_ + k], w, acc2);
    acc3 = fmaf(sA[3 * D_ + k], w, acc3);
  }
  const float bb = bias[t];
  out_f[(size_t)(row0 + 0) * O_ + t] = acc0 + bb;
  out_f[(size_t)(row0 + 1) * O_ + t] = acc1 + bb;
  out_f[(size_t)(row0 + 2) * O_ + t] = acc2 + bb;
  out_f[(size_t)(row0 + 3) * O_ + t] = acc3 + bb;

  // query_v gather: 4 rows x 9 floats
  if (t < RPB * 9) {
    const int r = t / 9;
    const int e = t - r * 9;
    out_v[(size_t)(row0 + r) * 9 + e] = pcd_v[(size_t)sIdx[r] * 9 + e];
  }
}

extern "C" void kernel_launch(void* const* d_in, const int* in_sizes, int n_in,
                              void* d_out, int out_size, void* d_ws, size_t ws_size,
                              hipStream_t stream) {
  const float* tgt   = (const float*)d_in[0];  // [4,16384,128]
  const float* pcd_x = (const float*)d_in[1];  // [4,16384,3]
  const float* pcd_v = (const float*)d_in[2];  // [4,16384,3,3]
  const float* W     = (const float*)d_in[3];  // [128,256]
  const float* bias  = (const float*)d_in[4];  // [256]

  float* out   = (float*)d_out;
  float* out_f = out;                                   // [4,1170,256]
  float* out_c = out + (size_t)B_ * NOUT * O_;          // [4,1170,3]
  float* out_v = out_c + (size_t)B_ * NOUT * 3;         // [4,1170,3,3]

  int* sel = (int*)d_ws;  // [4,1170] int32

  hipLaunchKernelGGL(fps_kernel, dim3(B_), dim3(TPB_FPS), 0, stream,
                     pcd_x, sel, out_c);
  hipLaunchKernelGGL(proj_kernel, dim3(B_ * NOUT / RPB), dim3(TPB_PROJ), 0, stream,
                     tgt, pcd_v, W, bias, sel, out_f, out_v);
}